// Round 15
// baseline (89.177 us; speedup 1.0000x reference)
//
#include <hip/hip_runtime.h>

#define NB   32
#define NCI  128
#define NH   64
#define NW   64
#define NCO  256
#define NOH  62
#define NOW  62

typedef __attribute__((ext_vector_type(8)))  short bf16x8;    // 8 bf16 (4 VGPRs)
typedef __attribute__((ext_vector_type(8)))  unsigned short u16x8;
typedef __attribute__((ext_vector_type(4)))  float f32x4;
typedef __attribute__((ext_vector_type(16))) float f32x16;

typedef __attribute__((address_space(1))) const unsigned int glb_u32_t;
typedef __attribute__((address_space(3))) unsigned int lds_u32_t;

// fp32 -> bf16 bits, round-to-nearest-even (finite inputs)
__device__ __forceinline__ unsigned short f2bf(float f) {
  unsigned int u = __float_as_uint(f);
  u = u + 0x7FFFu + ((u >> 16) & 1u);
  return (unsigned short)(u >> 16);
}

__device__ __forceinline__ void gload_lds16(const unsigned short* g, unsigned short* l) {
  __builtin_amdgcn_global_load_lds((glb_u32_t*)g, (lds_u32_t*)l, 16, 0, 0);
}

// W[co][ci][kh][kw] fp32 -> wt[k][co][ci] bf16, coalesced 16B stores
__global__ __launch_bounds__(256) void cvt_w_kernel(const float* __restrict__ wsrc,
                                                    unsigned short* __restrict__ wt) {
  int t = blockIdx.x * 256 + threadIdx.x;            // 0 .. 9*256*16-1
  int oc = t & 15, co = (t >> 4) & 255, k = t >> 12;
  const float* src = wsrc + ((size_t)co * NCI + oc * 8) * 9 + k;
  u16x8 v;
  #pragma unroll
  for (int j = 0; j < 8; ++j) v[j] = f2bf(src[j * 9]);
  *(u16x8*)(wt + ((size_t)k * NCO + co) * NCI + oc * 8) = v;
}

// Implicit direct conv — 32x32x16 bf16 MFMA (2495 vs 2075 TF ubench: 17%
// fewer matrix-pipe cycles than 16x16x32 for the same FLOPs, half the MFMA
// instructions), fused x fp32->bf16 transpose staging (R14), half-tap
// register pipeline with bfC/bfD ping-pong (R13).
// Block: 256 thr (4 waves wn 0..3), tile 128 cout x 4 oh x 64 ow; wave tile
// 128co x 64pix = 4 A-frags (mi: 32co) x 2 B-frags (ni: 32pix) x 2 khalf.
// Fragment maps (32x32x16): A row=lane&31, k=(lane>>5)*8+j -> data-octet =
// 2*khalf + (lane>>5); B col=lane&31 mirrored; D col=lane&31,
// row=(reg&3)+8*(reg>>2)+4*(lane>>5)  [m74/m101-verified].
// khalf toggles octet bit1 -> byte-bit5: addr(khalf1) = addr(khalf0) ^ 32
// (XOR swizzle commutes). 36 taps t = c*9 + t9. LDS 80 KB (2 blocks/CU):
//   xs: 2 x [6r][64w][4oct][8] (24 KB, parity c&1)  bytes [0, 49152)
//   ws: 4 x [128co][4oct][8]   (8 KB, slot t&3)     bytes [49152, 81920)
// Per tap: {x8 loads; stage_w(t+3)} then
//   half0: 8 MFMA (afX=khalf0 x bfc[0..1])  || read afY (khalf1, 4)
//   half1: 8 MFMA (afY x bfc[2..3])         || read afX(t+1) + bfn(t+1) (8)
// tap end: vmcnt(2) [retires ws(t+2)+x8, keeps ws(t+3)]; fused xwrite;
// lgkmcnt(0) on staging taps; s_barrier. WAR/RAW windows identical to R14
// (ring-4 ws depth-3; xs parity: write at taps 9c+2..7, read from 9c+9).
// Octet swizzle on both sides; xs w-overreads (w<=65) stay in-allocation,
// feed masked ow>=62 outputs only.
__global__ __launch_bounds__(256, 2) void conv_mfma_kernel(
    const float* __restrict__ x, const unsigned short* __restrict__ wt,
    const float* __restrict__ bias, float* __restrict__ out) {
  __shared__ unsigned short smem[40960];   // 81920 B

  const int tid  = threadIdx.x;
  const int lane = tid & 63;
  const int wid  = tid >> 6;    // 0..3
  const int wn   = wid;         // output row within quad (0..3)
  const int l31  = lane & 31;
  const int lo5  = lane >> 5;   // 0..1

  // XCD-bijective swizzle: grid 1024 = 8 * 128 exactly.
  const int bid0  = blockIdx.x;
  const int bid   = (bid0 & 7) * 128 + (bid0 >> 3);
  const int coutg = bid & 1;               // ((b*16 + ohg)*2 + coutg)
  const int ohg   = (bid >> 1) & 15;
  const int b     = bid >> 5;
  const int cbase = coutg * 128;
  const int oh0   = ohg * 4;               // 0..60 (ohg 15: rows 62,63 masked)

  f32x16 acc[4][2];
  #pragma unroll
  for (int mi = 0; mi < 4; ++mi)
    #pragma unroll
    for (int ni = 0; ni < 2; ++ni)
      acc[mi][ni] = (f32x16)(0.f);

  const char* sm = (const char*)smem;
  // A-frag per-lane base: co = mi*32 + l31 (mi static +2048B); khalf0 octet
  // = lo5 ^ ((co>>1)&3); (co>>1)&3 == (l31>>1)&3 (mi*32 clears bits 1-2).
  const int afb0 = l31 * 64 + ((lo5 ^ ((l31 >> 1) & 3)) << 4);
  const int afb1 = afb0 ^ 32;              // khalf1: octet bit1 -> byte bit5

  // x fp32 base for this batch image
  const float* xb = x + ((size_t)b * NCI) * (NH * NW);

  const unsigned short* wsrc2[2];
  #pragma unroll
  for (int i = 0; i < 2; ++i) {
    int e = (wid * 2 + i) * 64 + lane;     // 0..511
    int o = e & 3, co = e >> 2;            // co 0..127
    wsrc2[i] = wt + (size_t)(cbase + co) * NCI + ((o ^ ((co >> 1) & 3)) * 8);
  }

  // stage ws for global tap t into slot t&3: 2 gload/thread
  auto stage_w = [&](int t) {
    unsigned short* dst = smem + 24576 + (t & 3) * 4096;
    const size_t so = (size_t)(t % 9) * NCO * NCI + (t / 9) * 32;
    #pragma unroll
    for (int i = 0; i < 2; ++i)
      gload_lds16(wsrc2[i] + so, dst + ((wid * 2 + i) * 64 + lane) * 8);
  };

  // fused x staging: unit uu of chunk c1 = (row r, ci-octet oct, w = lane)
  auto xload8 = [&](int c1, int uu, float (&xf)[8]) {
    const int g = uu * 4 + wid;            // 0..23
    const int r = g % 6, oct = g / 6;
    int row = oh0 + r; if (row > 63) row = 63;       // clamp (masked outputs)
    const float* src = xb + (size_t)(c1 * 32 + oct * 8) * (NH * NW)
                     + row * NW + lane;
    #pragma unroll
    for (int j = 0; j < 8; ++j) xf[j] = src[(size_t)j * (NH * NW)];
  };
  auto xwrite8 = [&](int c1, int uu, float (&xf)[8]) {
    const int g = uu * 4 + wid;
    const int r = g % 6, oct = g / 6;
    u16x8 v;
    #pragma unroll
    for (int j = 0; j < 8; ++j) v[j] = f2bf(xf[j]);
    *(u16x8*)(smem + (c1 & 1) * 12288 +
              ((r * 64 + lane) * 4 + (oct ^ ((lane >> 1) & 3))) * 8) = v;
  };

  bf16x8 afX[4], afY[4], bfC[4], bfD[4];

  // one tap body; bfc = this tap's B-frags [khalf0:ni0,ni1, khalf1:ni0,ni1],
  // bfn = next tap's (filled by half1's interleaved reads when pf).
  auto tap_body = [&](int t, bf16x8 (&bfc)[4], bf16x8 (&bfn)[4], bool pf) {
    const int t9 = t % 9, c = t / 9;
    const bool xst = (t9 >= 2 && t9 <= 7) && (c < 3);
    float xf[8];

    if (xst) xload8(c + 1, t9 - 2, xf);
    __builtin_amdgcn_sched_barrier(0);
    if (t + 3 < 36) stage_w(t + 3);
    __builtin_amdgcn_sched_barrier(0);

    const char* wsp  = sm + 49152 + (t & 3) * 8192;        // this tap's ws
    const char* wspn = sm + 49152 + ((t + 1) & 3) * 8192;  // next tap's ws
    const int tn = t + 1, tn9 = tn % 9, cn = tn / 9;
    const int khn = tn9 / 3, kwn = tn9 - khn * 3;
    const char* xspn = sm + (cn & 1) * 24576 + (wn + khn) * 4096;
    const int w9n  = l31 + kwn;
    const int bfln = w9n * 64 + ((lo5 ^ ((w9n >> 1) & 3)) << 4);

    // ---- half 0 (khalf0): acc += afX x bfc[0..1]  ||  afY <- khalf1(t)
    asm volatile("s_waitcnt lgkmcnt(0)" ::: "memory");
    __builtin_amdgcn_sched_barrier(0);
    __builtin_amdgcn_s_setprio(1);
    acc[0][0] = __builtin_amdgcn_mfma_f32_32x32x16_bf16(afX[0], bfc[0], acc[0][0], 0, 0, 0);
    afY[0] = *(const bf16x8*)(wsp + 0 * 2048 + afb1);
    afY[1] = *(const bf16x8*)(wsp + 1 * 2048 + afb1);
    acc[0][1] = __builtin_amdgcn_mfma_f32_32x32x16_bf16(afX[0], bfc[1], acc[0][1], 0, 0, 0);
    afY[2] = *(const bf16x8*)(wsp + 2 * 2048 + afb1);
    afY[3] = *(const bf16x8*)(wsp + 3 * 2048 + afb1);
    acc[1][0] = __builtin_amdgcn_mfma_f32_32x32x16_bf16(afX[1], bfc[0], acc[1][0], 0, 0, 0);
    acc[1][1] = __builtin_amdgcn_mfma_f32_32x32x16_bf16(afX[1], bfc[1], acc[1][1], 0, 0, 0);
    acc[2][0] = __builtin_amdgcn_mfma_f32_32x32x16_bf16(afX[2], bfc[0], acc[2][0], 0, 0, 0);
    acc[2][1] = __builtin_amdgcn_mfma_f32_32x32x16_bf16(afX[2], bfc[1], acc[2][1], 0, 0, 0);
    acc[3][0] = __builtin_amdgcn_mfma_f32_32x32x16_bf16(afX[3], bfc[0], acc[3][0], 0, 0, 0);
    acc[3][1] = __builtin_amdgcn_mfma_f32_32x32x16_bf16(afX[3], bfc[1], acc[3][1], 0, 0, 0);
    __builtin_amdgcn_s_setprio(0);

    // ---- half 1 (khalf1): acc += afY x bfc[2..3]  ||  afX,bfn <- tap t+1
    asm volatile("s_waitcnt lgkmcnt(0)" ::: "memory");
    __builtin_amdgcn_sched_barrier(0);
    __builtin_amdgcn_s_setprio(1);
    acc[0][0] = __builtin_amdgcn_mfma_f32_32x32x16_bf16(afY[0], bfc[2], acc[0][0], 0, 0, 0);
    if (pf) { afX[0] = *(const bf16x8*)(wspn + 0 * 2048 + afb0);
              afX[1] = *(const bf16x8*)(wspn + 1 * 2048 + afb0); }
    acc[0][1] = __builtin_amdgcn_mfma_f32_32x32x16_bf16(afY[0], bfc[3], acc[0][1], 0, 0, 0);
    if (pf) { afX[2] = *(const bf16x8*)(wspn + 2 * 2048 + afb0);
              afX[3] = *(const bf16x8*)(wspn + 3 * 2048 + afb0); }
    acc[1][0] = __builtin_amdgcn_mfma_f32_32x32x16_bf16(afY[1], bfc[2], acc[1][0], 0, 0, 0);
    if (pf) { bfn[0] = *(const bf16x8*)(xspn + bfln);
              bfn[1] = *(const bf16x8*)(xspn + 2048 + bfln); }
    acc[1][1] = __builtin_amdgcn_mfma_f32_32x32x16_bf16(afY[1], bfc[3], acc[1][1], 0, 0, 0);
    if (pf) { bfn[2] = *(const bf16x8*)(xspn + (bfln ^ 32));
              bfn[3] = *(const bf16x8*)(xspn + 2048 + (bfln ^ 32)); }
    acc[2][0] = __builtin_amdgcn_mfma_f32_32x32x16_bf16(afY[2], bfc[2], acc[2][0], 0, 0, 0);
    acc[2][1] = __builtin_amdgcn_mfma_f32_32x32x16_bf16(afY[2], bfc[3], acc[2][1], 0, 0, 0);
    acc[3][0] = __builtin_amdgcn_mfma_f32_32x32x16_bf16(afY[3], bfc[2], acc[3][0], 0, 0, 0);
    acc[3][1] = __builtin_amdgcn_mfma_f32_32x32x16_bf16(afY[3], bfc[3], acc[3][1], 0, 0, 0);
    __builtin_amdgcn_s_setprio(0);

    // ---- tap end: counted vmcnt; fused x cvt+write; barrier
    if (t >= 33) { asm volatile("s_waitcnt vmcnt(0)" ::: "memory"); }
    else         { asm volatile("s_waitcnt vmcnt(2)" ::: "memory"); }
    if (xst) {
      xwrite8(c + 1, t9 - 2, xf);
      asm volatile("s_waitcnt lgkmcnt(0)" ::: "memory");
    }
    __builtin_amdgcn_s_barrier();
    __builtin_amdgcn_sched_barrier(0);
  };

  // prologue: chunk 0 (fused), ws slots 0,1,2; drain; initial frag fill
  {
    float xa[8], xbv[8], xc[8], xd[8], xe[8], xg[8];
    xload8(0, 0, xa); xload8(0, 1, xbv); xload8(0, 2, xc);
    xload8(0, 3, xd); xload8(0, 4, xe);  xload8(0, 5, xg);
    stage_w(0); stage_w(1); stage_w(2);
    asm volatile("s_waitcnt vmcnt(6)" ::: "memory");   // x48 retired
    xwrite8(0, 0, xa); xwrite8(0, 1, xbv); xwrite8(0, 2, xc);
    xwrite8(0, 3, xd); xwrite8(0, 4, xe);  xwrite8(0, 5, xg);
    asm volatile("s_waitcnt vmcnt(0) lgkmcnt(0)" ::: "memory");
    __builtin_amdgcn_s_barrier();
    __builtin_amdgcn_sched_barrier(0);
    const char* wsp0 = sm + 49152;
    #pragma unroll
    for (int mi = 0; mi < 4; ++mi)
      afX[mi] = *(const bf16x8*)(wsp0 + mi * 2048 + afb0);
    const char* xsp0 = sm + wn * 4096;     // t=0: c=0, kh=0, kw=0
    const int bfl0 = l31 * 64 + ((lo5 ^ ((l31 >> 1) & 3)) << 4);
    bfC[0] = *(const bf16x8*)(xsp0 + bfl0);
    bfC[1] = *(const bf16x8*)(xsp0 + 2048 + bfl0);
    bfC[2] = *(const bf16x8*)(xsp0 + (bfl0 ^ 32));
    bfC[3] = *(const bf16x8*)(xsp0 + 2048 + (bfl0 ^ 32));
  }

  for (int j = 0; j < 9; ++j) {
    const int t0 = 4 * j;
    tap_body(t0 + 0, bfC, bfD, true);
    tap_body(t0 + 1, bfD, bfC, true);
    tap_body(t0 + 2, bfC, bfD, true);
    tap_body(t0 + 3, bfD, bfC, j < 8);
  }

  // epilogue: D col = lane&31 (ow), row = (reg&3)+8*(reg>>2)+4*lo5 (cout)
  const int oh = oh0 + wn;
  if (oh < NOH) {
    const int ow0 = l31;
    #pragma unroll
    for (int mi = 0; mi < 4; ++mi)
      #pragma unroll
      for (int ni = 0; ni < 2; ++ni) {
        int ow = ni * 32 + ow0;
        if (ow < NOW) {
          #pragma unroll
          for (int rg = 0; rg < 4; ++rg) {
            int co0 = cbase + mi * 32 + 8 * rg + 4 * lo5;
            const f32x4 bv = *(const f32x4*)(bias + co0);
            size_t o0 = (((size_t)b * NCO + co0) * NOH + oh) * NOW + ow;
            const size_t cs = (size_t)NOH * NOW;
            out[o0]          = acc[mi][ni][4 * rg + 0] + bv[0];
            out[o0 + cs]     = acc[mi][ni][4 * rg + 1] + bv[1];
            out[o0 + 2 * cs] = acc[mi][ni][4 * rg + 2] + bv[2];
            out[o0 + 3 * cs] = acc[mi][ni][4 * rg + 3] + bv[3];
          }
        }
      }
  }
}

// Safety-net: correct fp32 direct conv (used only if ws_size too small)
__global__ __launch_bounds__(256) void conv_naive_kernel(
    const float* __restrict__ x, const float* __restrict__ w,
    const float* __restrict__ bias, float* __restrict__ out) {
  long t = (long)blockIdx.x * 256 + threadIdx.x;
  const long total = (long)NB * NCO * NOH * NOW;
  if (t >= total) return;
  int ow = (int)(t % NOW);
  int oh = (int)((t / NOW) % NOH);
  int co = (int)((t / ((long)NOW * NOH)) % NCO);
  int b  = (int)(t / ((long)NOW * NOH * NCO));
  float acc = bias[co];
  for (int ci = 0; ci < NCI; ++ci) {
    const float* xp = x + (((size_t)b * NCI + ci) * NH + oh) * NW + ow;
    const float* wp = w + ((size_t)co * NCI + ci) * 9;
    #pragma unroll
    for (int kh = 0; kh < 3; ++kh)
      #pragma unroll
      for (int kw = 0; kw < 3; ++kw)
        acc += xp[kh * NW + kw] * wp[kh * 3 + kw];
  }
  out[t] = acc;
}

extern "C" void kernel_launch(void* const* d_in, const int* in_sizes, int n_in,
                              void* d_out, int out_size, void* d_ws, size_t ws_size,
                              hipStream_t stream) {
  const float* x    = (const float*)d_in[0];
  const float* w    = (const float*)d_in[1];
  const float* bias = (const float*)d_in[2];
  float* out        = (float*)d_out;

  const size_t WT_BYTES = (size_t)9 * NCO * NCI * 2;             // 589824

  if (ws_size >= WT_BYTES) {
    unsigned short* wt = (unsigned short*)d_ws;
    cvt_w_kernel<<<(9 * NCO * 16) / 256, 256, 0, stream>>>(w, wt);
    conv_mfma_kernel<<<2 * 16 * NB, 256, 0, stream>>>(x, wt, bias, out);
  } else {
    const long total = (long)NB * NCO * NOH * NOW;
    conv_naive_kernel<<<(int)((total + 255) / 256), 256, 0, stream>>>(x, w, bias, out);
  }
}